// Round 1
// baseline (7762.507 us; speedup 1.0000x reference)
//
#include <hip/hip_runtime.h>
#include <hip/hip_bf16.h>

typedef __attribute__((ext_vector_type(4))) float f32x4;
typedef __attribute__((ext_vector_type(8))) short s16x8;
typedef __attribute__((ext_vector_type(4))) short s16x4;

#define DI __device__ __forceinline__

static constexpr int B_ = 8, S_ = 2048, E_ = 300, EP_ = 320, HD_ = 512, G4_ = 2048;
static constexpr int C_ = 8921, RNN_ = 1024, NROW_ = 16384;

DI float bf2f(unsigned short u){ unsigned int x = ((unsigned int)u) << 16; return __builtin_bit_cast(float, x); }
DI unsigned short f2bf(float f){
  unsigned int x = __builtin_bit_cast(unsigned int, f);
  x += 0x7fff + ((x >> 16) & 1);
  return (unsigned short)(x >> 16);
}
DI float sigm(float x){ return 1.f / (1.f + __expf(-x)); }
DI float tanh_f(float x){
  x = fminf(fmaxf(x, -15.f), 15.f);
  float e = __expf(2.f * x);
  return (e - 1.f) / (e + 1.f);
}
DI void gload16(const void* g, void* l){
  __builtin_amdgcn_global_load_lds((const __attribute__((address_space(1))) void*)g,
                                   (__attribute__((address_space(3))) void*)l, 16, 0, 0);
}

// ---------------- convert / pad fp32 -> bf16 ----------------
__global__ void k_cvt_pad(const float* __restrict__ src, unsigned short* __restrict__ dst,
                          int Rs, int Cs, int Cd){
  int r = blockIdx.x;
  long db = (long)r * Cd;
  for (int c = threadIdx.x; c < Cd; c += blockDim.x){
    float v = (r < Rs && c < Cs) ? src[(long)r * Cs + c] : 0.f;
    dst[db + c] = f2bf(v);
  }
}

// ---------------- embedding gather -> xe [S][B][EP] bf16 ----------------
__global__ void k_embed(const int* __restrict__ text, const float* __restrict__ emb,
                        unsigned short* __restrict__ xe){
  int m = blockIdx.x;            // m = s*8 + b
  int s = m >> 3, b = m & 7;
  int tok = text[b * S_ + s];
  const float* e = emb + (long)tok * E_;
  long db = (long)m * EP_;
  for (int c = threadIdx.x; c < EP_; c += blockDim.x){
    float v = (c < E_) ? e[c] : 0.f;
    xe[db + c] = f2bf(v);
  }
}

// ---------------- gemm_bt: C[M,N] = A[M,K] * Bt[N,K]^T  (bf16 in, fp32 acc) --------
// EPI: 0 = fp32 store, 1 = bf16 tanh, 2 = bf16 + bias, 3 = bf16
template<int EPI>
__global__ __launch_bounds__(256, 2)
void k_gemm_bt(const unsigned short* __restrict__ A, const unsigned short* __restrict__ Bt,
               void* __restrict__ Cout, int N, int K, int Mreal,
               long aBatch, long bBatch, long cBatch, const float* __restrict__ bias){
  __shared__ unsigned short As[128 * 32];
  __shared__ unsigned short Bs[128 * 32];
  const int tid = threadIdx.x, lane = tid & 63, wid = tid >> 6;
  const int wm = wid >> 1, wn = wid & 1;
  const int bm0 = blockIdx.y * 128, bn0 = blockIdx.x * 128;
  A  += (long)blockIdx.z * aBatch;
  Bt += (long)blockIdx.z * bBatch;

  f32x4 acc[4][4];
#pragma unroll
  for (int i = 0; i < 4; ++i)
#pragma unroll
    for (int jx = 0; jx < 4; ++jx) acc[i][jx] = f32x4{0.f, 0.f, 0.f, 0.f};

  for (int k0 = 0; k0 < K; k0 += 32){
    __syncthreads();
#pragma unroll
    for (int cc = 0; cc < 2; ++cc){
      int e = tid + cc * 256;               // 0..511 : 16B segment index
      int row = e >> 2, seg = e & 3;
      const unsigned short* ga = A + ((long)(bm0 + row)) * K + k0 + seg * 8;
      gload16(ga, (char*)As + cc * 4096 + wid * 1024);
      const unsigned short* gb = Bt + ((long)(bn0 + row)) * K + k0 + seg * 8;
      gload16(gb, (char*)Bs + cc * 4096 + wid * 1024);
    }
    __syncthreads();
    s16x8 af[4], bfr[4];
#pragma unroll
    for (int mt = 0; mt < 4; ++mt){
      int arow = wm * 64 + mt * 16 + (lane & 15);
      af[mt] = *(const s16x8*)((const char*)As + arow * 64 + (lane >> 4) * 16);
    }
#pragma unroll
    for (int nt = 0; nt < 4; ++nt){
      int brow = wn * 64 + nt * 16 + (lane & 15);
      bfr[nt] = *(const s16x8*)((const char*)Bs + brow * 64 + (lane >> 4) * 16);
    }
#pragma unroll
    for (int mt = 0; mt < 4; ++mt)
#pragma unroll
      for (int nt = 0; nt < 4; ++nt)
        acc[mt][nt] = __builtin_amdgcn_mfma_f32_16x16x32_bf16(af[mt], bfr[nt], acc[mt][nt], 0, 0, 0);
  }

  long co = (long)blockIdx.z * cBatch;
#pragma unroll
  for (int mt = 0; mt < 4; ++mt){
#pragma unroll
    for (int r = 0; r < 4; ++r){
      int row = bm0 + wm * 64 + mt * 16 + (lane >> 4) * 4 + r;
      if (row < Mreal){
#pragma unroll
        for (int nt = 0; nt < 4; ++nt){
          int col = bn0 + wn * 64 + nt * 16 + (lane & 15);
          float v = acc[mt][nt][r];
          long idx = co + (long)row * N + col;
          if constexpr (EPI == 0) ((float*)Cout)[idx] = v;
          else if constexpr (EPI == 1) ((unsigned short*)Cout)[idx] = f2bf(tanh_f(v));
          else if constexpr (EPI == 2) ((unsigned short*)Cout)[idx] = f2bf(v + bias[col]);
          else ((unsigned short*)Cout)[idx] = f2bf(v);
        }
      }
    }
  }
}

// ---------------- persistent bi-LSTM recurrence ----------------
// 32 WGs: wg<16 forward, wg>=16 backward. Each WG owns 32 h-dims (j0..j0+31) for all
// 8 batches; its 128 Whh rows (i,f,g,o quadruple) live in VGPRs as MFMA B-fragments.
__global__ __launch_bounds__(256, 1)
void k_lstm(const unsigned short* __restrict__ xw_all,
            const float* __restrict__ Whh_f, const float* __restrict__ Whh_b,
            unsigned short* __restrict__ Hb, int* __restrict__ flagsBase){
  __shared__ unsigned short hA[16 * 512];   // A tile [16 rows=batch][512 k], swizzled
  __shared__ float gl[8 * 128];             // gate results [batch][128 local gates]
  char* hAc = (char*)hA;
  const int tid = threadIdx.x, lane = tid & 63, wave = tid >> 6;
  const int wg = blockIdx.x;
  const int dir = wg >> 4, w16 = wg & 15;
  const int j0 = w16 * 32;
  const int b8 = tid >> 5, j = tid & 31;
  const float* Whh = dir ? Whh_b : Whh_f;
  const unsigned short* xw = xw_all + (long)dir * NROW_ * G4_;
  int* flags = flagsBase + dir * S_;

  // preload Whh slice into register B-fragments. local gate row lr = q*32 + jj
  s16x8 Bf0[16], Bf1[16];
  {
    int lr0 = wave * 32 + (lane & 15);
    int lr1 = lr0 + 16;
    int kg = (lane >> 4) * 8;
    const float* r0 = Whh + (long)((lr0 >> 5) * 512 + j0 + (lr0 & 31)) * 512;
    const float* r1 = Whh + (long)((lr1 >> 5) * 512 + j0 + (lr1 & 31)) * 512;
#pragma unroll
    for (int kt = 0; kt < 16; ++kt){
      s16x8 v0, v1;
#pragma unroll
      for (int i = 0; i < 8; ++i){
        v0[i] = (short)f2bf(r0[kt * 32 + kg + i]);
        v1[i] = (short)f2bf(r1[kt * 32 + kg + i]);
      }
      Bf0[kt] = v0; Bf1[kt] = v1;
    }
  }
  for (int i = tid; i < 16 * 512; i += 256) hA[i] = 0;

  float creg = 0.f;
  float xwi, xwf, xwg, xwo;
  {
    int s0 = dir ? (S_ - 1) : 0;
    long base = ((long)s0 * 8 + b8) * G4_ + j0 + j;
    xwi = bf2f(xw[base]); xwf = bf2f(xw[base + 512]);
    xwg = bf2f(xw[base + 1024]); xwo = bf2f(xw[base + 1536]);
  }
  __syncthreads();

  for (int t = 0; t < S_; ++t){
    int s = dir ? (S_ - 1 - t) : t;
    if (t > 0){
      if (tid == 0){
        while (__hip_atomic_load(&flags[t - 1], __ATOMIC_RELAXED, __HIP_MEMORY_SCOPE_AGENT) < 16)
          __builtin_amdgcn_s_sleep(2);
      }
      __syncthreads();
      __builtin_amdgcn_fence(__ATOMIC_ACQUIRE, "agent");
      int sp = dir ? (s + 1) : (s - 1);
#pragma unroll
      for (int cc = 0; cc < 2; ++cc){
        int i16 = tid + cc * 256;           // 512 x 16B = 8 rows x 1KB
        int bp = i16 >> 6, seg = i16 & 63;
        const uint4* gp = (const uint4*)(Hb + ((long)bp * S_ + sp) * RNN_ + dir * HD_) + seg;
        uint4 val = *gp;
        int byt = (bp * 1024 + seg * 16) ^ ((bp & 7) << 4);
        *(uint4*)(hAc + byt) = val;
      }
      __syncthreads();
    }

    // gates[16(batch,pad)][128] += hA * Whh_slice^T
    f32x4 acc0 = {0.f, 0.f, 0.f, 0.f}, acc1 = {0.f, 0.f, 0.f, 0.f};
    {
      int arow = lane & 15;
      int sw = (arow & 7) << 4;
      int kg16 = (lane >> 4) * 16;
#pragma unroll
      for (int kt = 0; kt < 16; ++kt){
        int ab = (arow * 1024 + kt * 64 + kg16) ^ sw;
        s16x8 afr = *(const s16x8*)(hAc + ab);
        acc0 = __builtin_amdgcn_mfma_f32_16x16x32_bf16(afr, Bf0[kt], acc0, 0, 0, 0);
        acc1 = __builtin_amdgcn_mfma_f32_16x16x32_bf16(afr, Bf1[kt], acc1, 0, 0, 0);
      }
    }
    {
      int colb = wave * 32 + (lane & 15);
      int rb = (lane >> 4) * 4;
#pragma unroll
      for (int r = 0; r < 4; ++r){
        int row = rb + r;
        if (row < 8){
          gl[row * 128 + colb] = acc0[r];
          gl[row * 128 + colb + 16] = acc1[r];
        }
      }
    }
    __syncthreads();
    {
      float gi = gl[b8 * 128 + j]      + xwi;
      float gf = gl[b8 * 128 + 32 + j] + xwf;
      float gg = gl[b8 * 128 + 64 + j] + xwg;
      float go = gl[b8 * 128 + 96 + j] + xwo;
      creg = sigm(gf) * creg + sigm(gi) * tanh_f(gg);
      float hv = sigm(go) * tanh_f(creg);
      Hb[((long)b8 * S_ + s) * RNN_ + dir * HD_ + j0 + j] = f2bf(hv);
    }
    __syncthreads();
    if (tid == 0){
      __builtin_amdgcn_fence(__ATOMIC_RELEASE, "agent");
      __hip_atomic_fetch_add(&flags[t], 1, __ATOMIC_RELAXED, __HIP_MEMORY_SCOPE_AGENT);
    }
    if (t + 1 < S_){
      int sn = dir ? (s - 1) : (s + 1);
      long base = ((long)sn * 8 + b8) * G4_ + j0 + j;
      xwi = bf2f(xw[base]); xwf = bf2f(xw[base + 512]);
      xwg = bf2f(xw[base + 1024]); xwo = bf2f(xw[base + 1536]);
    }
  }
}

// ---------------- fused softmax (over s) + logits ----------------
__global__ __launch_bounds__(256)
void k_softmax_logits(float* __restrict__ alpha, const unsigned short* __restrict__ HOt,
                      const float* __restrict__ Ob, float* __restrict__ logits){
  const int lane = threadIdx.x & 63, wv = threadIdx.x >> 6;
  long row = (long)blockIdx.x * 4 + wv;       // row = b*C + c
  float* a = alpha + row * (long)S_;
  const unsigned short* h = HOt + row * (long)S_;
  float v[32];
  float mx = -1e30f;
#pragma unroll
  for (int jj = 0; jj < 8; ++jj){
    f32x4 t = *(const f32x4*)(a + jj * 256 + lane * 4);
#pragma unroll
    for (int r = 0; r < 4; ++r){ v[jj * 4 + r] = t[r]; mx = fmaxf(mx, t[r]); }
  }
#pragma unroll
  for (int o = 32; o > 0; o >>= 1) mx = fmaxf(mx, __shfl_xor(mx, o));
  float sum = 0.f;
#pragma unroll
  for (int i = 0; i < 32; ++i){ v[i] = __expf(v[i] - mx); sum += v[i]; }
#pragma unroll
  for (int o = 32; o > 0; o >>= 1) sum += __shfl_xor(sum, o);
  float inv = 1.f / sum;
  float dot = 0.f;
#pragma unroll
  for (int jj = 0; jj < 8; ++jj){
    s16x4 hv = *(const s16x4*)(h + jj * 256 + lane * 4);
    f32x4 av;
#pragma unroll
    for (int r = 0; r < 4; ++r){
      float al = v[jj * 4 + r] * inv;
      av[r] = al;
      dot += al * bf2f((unsigned short)hv[r]);
    }
    *(f32x4*)(a + jj * 256 + lane * 4) = av;
  }
#pragma unroll
  for (int o = 32; o > 0; o >>= 1) dot += __shfl_xor(dot, o);
  if (lane == 0){
    int c = (int)(row % C_);
    logits[row] = dot + Ob[c];
  }
}

// ---------------- host ----------------
extern "C" void kernel_launch(void* const* d_in, const int* in_sizes, int n_in,
                              void* d_out, int out_size, void* d_ws, size_t ws_size,
                              hipStream_t stream){
  const int*   text  = (const int*)d_in[0];
  const float* emb   = (const float*)d_in[2];
  const float* Wih_f = (const float*)d_in[3];
  const float* Whh_f = (const float*)d_in[4];
  const float* b_f   = (const float*)d_in[5];
  const float* Wih_b = (const float*)d_in[6];
  const float* Whh_b = (const float*)d_in[7];
  const float* b_b   = (const float*)d_in[8];
  const float* Ww    = (const float*)d_in[9];
  const float* Qw    = (const float*)d_in[10];
  const float* Ow    = (const float*)d_in[11];
  const float* Ob    = (const float*)d_in[12];

  char* ws = (char*)d_ws;
  long o = 0;
  unsigned short* wWihF = (unsigned short*)(ws + o); o += 2048L * 320 * 2;
  unsigned short* wWihB = (unsigned short*)(ws + o); o += 2048L * 320 * 2;
  unsigned short* wWw   = (unsigned short*)(ws + o); o += 512L * 1024 * 2;
  unsigned short* wQw   = (unsigned short*)(ws + o); o += 8960L * 512 * 2;
  unsigned short* wOw   = (unsigned short*)(ws + o); o += 8960L * 1024 * 2;
  unsigned short* wH    = (unsigned short*)(ws + o); o += 8L * 2048 * 1024 * 2;
  unsigned short* wZ    = (unsigned short*)(ws + o); o += 16384L * 512 * 2;
  int* wFlags           = (int*)(ws + o);            o += 2L * 2048 * 4;
  char* regA = ws + o;                                // reused region
  unsigned short* wXe  = (unsigned short*)regA;                         // [16384][320]
  unsigned short* wXw  = (unsigned short*)(regA + 16384L * 320 * 2);    // [2][16384][2048]
  unsigned short* wHOt = (unsigned short*)regA;                         // [8][8921][2048] (after LSTM)

  float* logits = (float*)d_out;
  float* alpha  = logits + 8L * C_;    // [8][8921][2048], also holds raw scores

  hipMemsetAsync(wFlags, 0, 2L * 2048 * 4, stream);
  k_cvt_pad<<<2048, 256, 0, stream>>>(Wih_f, wWihF, 2048, 300, 320);
  k_cvt_pad<<<2048, 256, 0, stream>>>(Wih_b, wWihB, 2048, 300, 320);
  k_cvt_pad<<<512,  256, 0, stream>>>(Ww, wWw, 512, 1024, 1024);
  k_cvt_pad<<<8960, 256, 0, stream>>>(Qw, wQw, 8921, 512, 512);
  k_cvt_pad<<<8960, 256, 0, stream>>>(Ow, wOw, 8921, 1024, 1024);
  k_embed<<<16384, 256, 0, stream>>>(text, emb, wXe);

  // xw[dir] = xe @ Wih^T + b  -> bf16 [16384][2048]
  k_gemm_bt<2><<<dim3(16, 128, 1), 256, 0, stream>>>(wXe, wWihF, wXw, 2048, 320, 16384, 0, 0, 0, b_f);
  k_gemm_bt<2><<<dim3(16, 128, 1), 256, 0, stream>>>(wXe, wWihB, wXw + 16384L * 2048, 2048, 320, 16384, 0, 0, 0, b_b);

  k_lstm<<<32, 256, 0, stream>>>(wXw, Whh_f, Whh_b, wH, wFlags);

  // Z = tanh(H @ Ww^T)  [16384][512] bf16
  k_gemm_bt<1><<<dim3(4, 128, 1), 256, 0, stream>>>(wH, wWw, wZ, 512, 1024, 16384, 0, 0, 0, nullptr);
  // scores[b] = Qw @ Z[b]^T  -> fp32 into alpha region
  k_gemm_bt<0><<<dim3(16, 70, 8), 256, 0, stream>>>(wQw, wZ, alpha, 2048, 512, C_, 0, 2048L * 512, (long)C_ * 2048, nullptr);
  // HOt[b] = Ow @ H[b]^T  -> bf16
  k_gemm_bt<3><<<dim3(16, 70, 8), 256, 0, stream>>>(wOw, wH, wHOt, 2048, 1024, C_, 0, 2048L * 1024, (long)C_ * 2048, nullptr);

  k_softmax_logits<<<17842, 256, 0, stream>>>(alpha, wHOt, Ob, logits);
}

// Round 2
// 6507.729 us; speedup vs baseline: 1.1928x; 1.1928x over previous
//
#include <hip/hip_runtime.h>
#include <hip/hip_bf16.h>

typedef __attribute__((ext_vector_type(4))) float f32x4;
typedef __attribute__((ext_vector_type(8))) short s16x8;
typedef __attribute__((ext_vector_type(4))) short s16x4;

#define DI __device__ __forceinline__

static constexpr int B_ = 8, S_ = 2048, E_ = 300, EP_ = 320, HD_ = 512, G4_ = 2048;
static constexpr int C_ = 8921, RNN_ = 1024, NROW_ = 16384;

DI float bf2f(unsigned short u){ unsigned int x = ((unsigned int)u) << 16; return __builtin_bit_cast(float, x); }
DI unsigned short f2bf(float f){
  unsigned int x = __builtin_bit_cast(unsigned int, f);
  x += 0x7fff + ((x >> 16) & 1);
  return (unsigned short)(x >> 16);
}
DI float sigm(float x){ return 1.f / (1.f + __expf(-x)); }
DI float tanh_f(float x){
  x = fminf(fmaxf(x, -15.f), 15.f);
  float e = __expf(2.f * x);
  return (e - 1.f) / (e + 1.f);
}
DI void gload16(const void* g, void* l){
  __builtin_amdgcn_global_load_lds((const __attribute__((address_space(1))) void*)g,
                                   (__attribute__((address_space(3))) void*)l, 16, 0, 0);
}

// ---------------- convert / pad fp32 -> bf16 ----------------
__global__ void k_cvt_pad(const float* __restrict__ src, unsigned short* __restrict__ dst,
                          int Rs, int Cs, int Cd){
  int r = blockIdx.x;
  long db = (long)r * Cd;
  for (int c = threadIdx.x; c < Cd; c += blockDim.x){
    float v = (r < Rs && c < Cs) ? src[(long)r * Cs + c] : 0.f;
    dst[db + c] = f2bf(v);
  }
}

// ---------------- embedding gather -> xe [S][B][EP] bf16 ----------------
__global__ void k_embed(const int* __restrict__ text, const float* __restrict__ emb,
                        unsigned short* __restrict__ xe){
  int m = blockIdx.x;            // m = s*8 + b
  int s = m >> 3, b = m & 7;
  int tok = text[b * S_ + s];
  const float* e = emb + (long)tok * E_;
  long db = (long)m * EP_;
  for (int c = threadIdx.x; c < EP_; c += blockDim.x){
    float v = (c < E_) ? e[c] : 0.f;
    xe[db + c] = f2bf(v);
  }
}

// ---------------- gemm_bt: C[M,N] = A[M,K] * Bt[N,K]^T  (bf16 in, fp32 acc) --------
// EPI: 0 = fp32 store, 1 = bf16 tanh, 2 = bf16 + bias, 3 = bf16
template<int EPI>
__global__ __launch_bounds__(256, 2)
void k_gemm_bt(const unsigned short* __restrict__ A, const unsigned short* __restrict__ Bt,
               void* __restrict__ Cout, int N, int K, int Mreal,
               long aBatch, long bBatch, long cBatch, const float* __restrict__ bias){
  __shared__ unsigned short As[128 * 32];
  __shared__ unsigned short Bs[128 * 32];
  const int tid = threadIdx.x, lane = tid & 63, wid = tid >> 6;
  const int wm = wid >> 1, wn = wid & 1;
  const int bm0 = blockIdx.y * 128, bn0 = blockIdx.x * 128;
  A  += (long)blockIdx.z * aBatch;
  Bt += (long)blockIdx.z * bBatch;

  f32x4 acc[4][4];
#pragma unroll
  for (int i = 0; i < 4; ++i)
#pragma unroll
    for (int jx = 0; jx < 4; ++jx) acc[i][jx] = f32x4{0.f, 0.f, 0.f, 0.f};

  for (int k0 = 0; k0 < K; k0 += 32){
    __syncthreads();
#pragma unroll
    for (int cc = 0; cc < 2; ++cc){
      int e = tid + cc * 256;               // 0..511 : 16B segment index
      int row = e >> 2, seg = e & 3;
      const unsigned short* ga = A + ((long)(bm0 + row)) * K + k0 + seg * 8;
      gload16(ga, (char*)As + cc * 4096 + wid * 1024);
      const unsigned short* gb = Bt + ((long)(bn0 + row)) * K + k0 + seg * 8;
      gload16(gb, (char*)Bs + cc * 4096 + wid * 1024);
    }
    __syncthreads();
    s16x8 af[4], bfr[4];
#pragma unroll
    for (int mt = 0; mt < 4; ++mt){
      int arow = wm * 64 + mt * 16 + (lane & 15);
      af[mt] = *(const s16x8*)((const char*)As + arow * 64 + (lane >> 4) * 16);
    }
#pragma unroll
    for (int nt = 0; nt < 4; ++nt){
      int brow = wn * 64 + nt * 16 + (lane & 15);
      bfr[nt] = *(const s16x8*)((const char*)Bs + brow * 64 + (lane >> 4) * 16);
    }
#pragma unroll
    for (int mt = 0; mt < 4; ++mt)
#pragma unroll
      for (int nt = 0; nt < 4; ++nt)
        acc[mt][nt] = __builtin_amdgcn_mfma_f32_16x16x32_bf16(af[mt], bfr[nt], acc[mt][nt], 0, 0, 0);
  }

  long co = (long)blockIdx.z * cBatch;
#pragma unroll
  for (int mt = 0; mt < 4; ++mt){
#pragma unroll
    for (int r = 0; r < 4; ++r){
      int row = bm0 + wm * 64 + mt * 16 + (lane >> 4) * 4 + r;
      if (row < Mreal){
#pragma unroll
        for (int nt = 0; nt < 4; ++nt){
          int col = bn0 + wn * 64 + nt * 16 + (lane & 15);
          float v = acc[mt][nt][r];
          long idx = co + (long)row * N + col;
          if constexpr (EPI == 0) ((float*)Cout)[idx] = v;
          else if constexpr (EPI == 1) ((unsigned short*)Cout)[idx] = f2bf(tanh_f(v));
          else if constexpr (EPI == 2) ((unsigned short*)Cout)[idx] = f2bf(v + bias[col]);
          else ((unsigned short*)Cout)[idx] = f2bf(v);
        }
      }
    }
  }
}

// ---------------- persistent bi-LSTM recurrence ----------------
// 32 WGs: wg<16 forward, wg>=16 backward. Each WG owns 32 h-dims (j0..j0+31) for all
// 8 batches; its 128 Whh rows (i,f,g,o quadruple) live in VGPRs as MFMA B-fragments.
// Cross-WG handshake: NO fences (agent fences lower to whole-L2 buffer_inv/wbl2).
// Producers write h with sc0+sc1 (write-through to coherent point) + vmcnt(0),
// then one per-producer tag store (sc0 sc1). Consumers poll the 16 tags in
// parallel and read h with sc0+sc1 loads. Addresses are step-unique -> no ABA.
__global__ __launch_bounds__(256, 1)
void k_lstm(const unsigned short* __restrict__ xw_all,
            const float* __restrict__ Whh_f, const float* __restrict__ Whh_b,
            unsigned short* __restrict__ Hb, int* __restrict__ tagsBase){
  __shared__ unsigned short hA[16 * 512];   // A tile [16 rows=batch][512 k], swizzled
  __shared__ float gl[8 * 128];             // gate results [batch][128 local gates]
  char* hAc = (char*)hA;
  const int tid = threadIdx.x, lane = tid & 63, wave = tid >> 6;
  const int wg = blockIdx.x;
  const int dir = wg >> 4, w16 = wg & 15;
  const int j0 = w16 * 32;
  const int b8 = tid >> 5, j = tid & 31;
  const float* Whh = dir ? Whh_b : Whh_f;
  const unsigned short* xw = xw_all + (long)dir * NROW_ * G4_;
  int* tags = tagsBase + dir * 16 * 16;     // [16 producers][16 ints = 64B each]

  // preload Whh slice into register B-fragments. local gate row lr = q*32 + jj
  s16x8 Bf0[16], Bf1[16];
  {
    int lr0 = wave * 32 + (lane & 15);
    int lr1 = lr0 + 16;
    int kg = (lane >> 4) * 8;
    const float* r0 = Whh + (long)((lr0 >> 5) * 512 + j0 + (lr0 & 31)) * 512;
    const float* r1 = Whh + (long)((lr1 >> 5) * 512 + j0 + (lr1 & 31)) * 512;
#pragma unroll
    for (int kt = 0; kt < 16; ++kt){
      s16x8 v0, v1;
#pragma unroll
      for (int i = 0; i < 8; ++i){
        v0[i] = (short)f2bf(r0[kt * 32 + kg + i]);
        v1[i] = (short)f2bf(r1[kt * 32 + kg + i]);
      }
      Bf0[kt] = v0; Bf1[kt] = v1;
    }
  }
  for (int i = tid; i < 16 * 512; i += 256) hA[i] = 0;

  float creg = 0.f;
  float xwi, xwf, xwg, xwo;
  {
    int s0 = dir ? (S_ - 1) : 0;
    long base = ((long)s0 * 8 + b8) * G4_ + j0 + j;
    xwi = bf2f(xw[base]); xwf = bf2f(xw[base + 512]);
    xwg = bf2f(xw[base + 1024]); xwo = bf2f(xw[base + 1536]);
  }
  __syncthreads();

  for (int t = 0; t < S_; ++t){
    int s = dir ? (S_ - 1 - t) : t;
    if (t > 0){
      // ---- wait: all 16 producers of this dir have published step t-1 (tag >= t)
      if (wave == 0){
        const int* tp = tags + (lane & 15) * 16;
        for (;;){
          int v;
          asm volatile("global_load_dword %0, %1, off sc0 sc1\n\t"
                       "s_waitcnt vmcnt(0)"
                       : "=v"(v) : "v"(tp) : "memory");
          if (__all(v >= t)) break;
          __builtin_amdgcn_s_sleep(1);
        }
      }
      __syncthreads();
      // ---- load h(t-1): 256 threads x 32B, sc0+sc1 (fresh from coherent point)
      int sp = dir ? (s + 1) : (s - 1);
      const uint4* gp0; const uint4* gp1;
      {
        int bp0 = tid >> 6,        seg0 = tid & 63;
        int bp1 = (tid + 256) >> 6, seg1 = (tid + 256) & 63;
        gp0 = (const uint4*)(Hb + ((long)bp0 * S_ + sp) * RNN_ + dir * HD_) + seg0;
        gp1 = (const uint4*)(Hb + ((long)bp1 * S_ + sp) * RNN_ + dir * HD_) + seg1;
      }
      uint4 va0, va1;
      asm volatile("global_load_dwordx4 %0, %2, off sc0 sc1\n\t"
                   "global_load_dwordx4 %1, %3, off sc0 sc1\n\t"
                   "s_waitcnt vmcnt(0)"
                   : "=&v"(va0), "=&v"(va1) : "v"(gp0), "v"(gp1) : "memory");
      __builtin_amdgcn_sched_barrier(0);
#pragma unroll
      for (int cc = 0; cc < 2; ++cc){
        int i16 = tid + cc * 256;
        int bp = i16 >> 6, seg = i16 & 63;
        int byt = (bp * 1024 + seg * 16) ^ ((bp & 7) << 4);
        *(uint4*)(hAc + byt) = cc ? va1 : va0;
      }
      __syncthreads();
    }

    // gates[16(batch,pad)][128] += hA * Whh_slice^T
    f32x4 acc0 = {0.f, 0.f, 0.f, 0.f}, acc1 = {0.f, 0.f, 0.f, 0.f};
    {
      int arow = lane & 15;
      int sw = (arow & 7) << 4;
      int kg16 = (lane >> 4) * 16;
#pragma unroll
      for (int kt = 0; kt < 16; ++kt){
        int ab = (arow * 1024 + kt * 64 + kg16) ^ sw;
        s16x8 afr = *(const s16x8*)(hAc + ab);
        acc0 = __builtin_amdgcn_mfma_f32_16x16x32_bf16(afr, Bf0[kt], acc0, 0, 0, 0);
        acc1 = __builtin_amdgcn_mfma_f32_16x16x32_bf16(afr, Bf1[kt], acc1, 0, 0, 0);
      }
    }
    {
      int colb = wave * 32 + (lane & 15);
      int rb = (lane >> 4) * 4;
#pragma unroll
      for (int r = 0; r < 4; ++r){
        int row = rb + r;
        if (row < 8){
          gl[row * 128 + colb] = acc0[r];
          gl[row * 128 + colb + 16] = acc1[r];
        }
      }
    }
    __syncthreads();
    {
      float gi = gl[b8 * 128 + j]      + xwi;
      float gf = gl[b8 * 128 + 32 + j] + xwf;
      float gg = gl[b8 * 128 + 64 + j] + xwg;
      float go = gl[b8 * 128 + 96 + j] + xwo;
      creg = sigm(gf) * creg + sigm(gi) * tanh_f(gg);
      float hv = sigm(go) * tanh_f(creg);
      // prefetch next step's xw before waiting on the store ack (overlaps L3 RT)
      if (t + 1 < S_){
        int sn = dir ? (s - 1) : (s + 1);
        long base = ((long)sn * 8 + b8) * G4_ + j0 + j;
        xwi = bf2f(xw[base]); xwf = bf2f(xw[base + 512]);
        xwg = bf2f(xw[base + 1024]); xwo = bf2f(xw[base + 1536]);
      }
      unsigned short* hp = Hb + ((long)b8 * S_ + s) * RNN_ + dir * HD_ + j0 + j;
      unsigned hd = (unsigned)f2bf(hv);
      asm volatile("global_store_short %0, %1, off sc0 sc1\n\t"
                   "s_waitcnt vmcnt(0)"
                   :: "v"(hp), "v"(hd) : "memory");
    }
    __syncthreads();
    if (tid == 0){
      int* tp = tags + w16 * 16;
      unsigned tv = (unsigned)(t + 1);
      asm volatile("global_store_dword %0, %1, off sc0 sc1"
                   :: "v"(tp), "v"(tv) : "memory");
    }
  }
}

// ---------------- fused softmax (over s) + logits ----------------
__global__ __launch_bounds__(256)
void k_softmax_logits(float* __restrict__ alpha, const unsigned short* __restrict__ HOt,
                      const float* __restrict__ Ob, float* __restrict__ logits){
  const int lane = threadIdx.x & 63, wv = threadIdx.x >> 6;
  long row = (long)blockIdx.x * 4 + wv;       // row = b*C + c
  float* a = alpha + row * (long)S_;
  const unsigned short* h = HOt + row * (long)S_;
  float v[32];
  float mx = -1e30f;
#pragma unroll
  for (int jj = 0; jj < 8; ++jj){
    f32x4 t = *(const f32x4*)(a + jj * 256 + lane * 4);
#pragma unroll
    for (int r = 0; r < 4; ++r){ v[jj * 4 + r] = t[r]; mx = fmaxf(mx, t[r]); }
  }
#pragma unroll
  for (int o = 32; o > 0; o >>= 1) mx = fmaxf(mx, __shfl_xor(mx, o));
  float sum = 0.f;
#pragma unroll
  for (int i = 0; i < 32; ++i){ v[i] = __expf(v[i] - mx); sum += v[i]; }
#pragma unroll
  for (int o = 32; o > 0; o >>= 1) sum += __shfl_xor(sum, o);
  float inv = 1.f / sum;
  float dot = 0.f;
#pragma unroll
  for (int jj = 0; jj < 8; ++jj){
    s16x4 hv = *(const s16x4*)(h + jj * 256 + lane * 4);
    f32x4 av;
#pragma unroll
    for (int r = 0; r < 4; ++r){
      float al = v[jj * 4 + r] * inv;
      av[r] = al;
      dot += al * bf2f((unsigned short)hv[r]);
    }
    *(f32x4*)(a + jj * 256 + lane * 4) = av;
  }
#pragma unroll
  for (int o = 32; o > 0; o >>= 1) dot += __shfl_xor(dot, o);
  if (lane == 0){
    int c = (int)(row % C_);
    logits[row] = dot + Ob[c];
  }
}

// ---------------- host ----------------
extern "C" void kernel_launch(void* const* d_in, const int* in_sizes, int n_in,
                              void* d_out, int out_size, void* d_ws, size_t ws_size,
                              hipStream_t stream){
  const int*   text  = (const int*)d_in[0];
  const float* emb   = (const float*)d_in[2];
  const float* Wih_f = (const float*)d_in[3];
  const float* Whh_f = (const float*)d_in[4];
  const float* b_f   = (const float*)d_in[5];
  const float* Wih_b = (const float*)d_in[6];
  const float* Whh_b = (const float*)d_in[7];
  const float* b_b   = (const float*)d_in[8];
  const float* Ww    = (const float*)d_in[9];
  const float* Qw    = (const float*)d_in[10];
  const float* Ow    = (const float*)d_in[11];
  const float* Ob    = (const float*)d_in[12];

  char* ws = (char*)d_ws;
  long o = 0;
  unsigned short* wWihF = (unsigned short*)(ws + o); o += 2048L * 320 * 2;
  unsigned short* wWihB = (unsigned short*)(ws + o); o += 2048L * 320 * 2;
  unsigned short* wWw   = (unsigned short*)(ws + o); o += 512L * 1024 * 2;
  unsigned short* wQw   = (unsigned short*)(ws + o); o += 8960L * 512 * 2;
  unsigned short* wOw   = (unsigned short*)(ws + o); o += 8960L * 1024 * 2;
  unsigned short* wH    = (unsigned short*)(ws + o); o += 8L * 2048 * 1024 * 2;
  unsigned short* wZ    = (unsigned short*)(ws + o); o += 16384L * 512 * 2;
  int* wTags            = (int*)(ws + o);            o += 2L * 16 * 16 * 4;
  char* regA = ws + o;                                // reused region
  unsigned short* wXe  = (unsigned short*)regA;                         // [16384][320]
  unsigned short* wXw  = (unsigned short*)(regA + 16384L * 320 * 2);    // [2][16384][2048]
  unsigned short* wHOt = (unsigned short*)regA;                         // [8][8921][2048] (after LSTM)

  float* logits = (float*)d_out;
  float* alpha  = logits + 8L * C_;    // [8][8921][2048], also holds raw scores

  hipMemsetAsync(wTags, 0, 2L * 16 * 16 * 4, stream);
  k_cvt_pad<<<2048, 256, 0, stream>>>(Wih_f, wWihF, 2048, 300, 320);
  k_cvt_pad<<<2048, 256, 0, stream>>>(Wih_b, wWihB, 2048, 300, 320);
  k_cvt_pad<<<512,  256, 0, stream>>>(Ww, wWw, 512, 1024, 1024);
  k_cvt_pad<<<8960, 256, 0, stream>>>(Qw, wQw, 8921, 512, 512);
  k_cvt_pad<<<8960, 256, 0, stream>>>(Ow, wOw, 8921, 1024, 1024);
  k_embed<<<16384, 256, 0, stream>>>(text, emb, wXe);

  // xw[dir] = xe @ Wih^T + b  -> bf16 [16384][2048]
  k_gemm_bt<2><<<dim3(16, 128, 1), 256, 0, stream>>>(wXe, wWihF, wXw, 2048, 320, 16384, 0, 0, 0, b_f);
  k_gemm_bt<2><<<dim3(16, 128, 1), 256, 0, stream>>>(wXe, wWihB, wXw + 16384L * 2048, 2048, 320, 16384, 0, 0, 0, b_b);

  k_lstm<<<32, 256, 0, stream>>>(wXw, Whh_f, Whh_b, wH, wTags);

  // Z = tanh(H @ Ww^T)  [16384][512] bf16
  k_gemm_bt<1><<<dim3(4, 128, 1), 256, 0, stream>>>(wH, wWw, wZ, 512, 1024, 16384, 0, 0, 0, nullptr);
  // scores[b] = Qw @ Z[b]^T  -> fp32 into alpha region
  k_gemm_bt<0><<<dim3(16, 70, 8), 256, 0, stream>>>(wQw, wZ, alpha, 2048, 512, C_, 0, 2048L * 512, (long)C_ * 2048, nullptr);
  // HOt[b] = Ow @ H[b]^T  -> bf16
  k_gemm_bt<3><<<dim3(16, 70, 8), 256, 0, stream>>>(wOw, wH, wHOt, 2048, 1024, C_, 0, 2048L * 1024, (long)C_ * 2048, nullptr);

  k_softmax_logits<<<17842, 256, 0, stream>>>(alpha, wHOt, Ob, logits);
}

// Round 3
// 4887.023 us; speedup vs baseline: 1.5884x; 1.3316x over previous
//
#include <hip/hip_runtime.h>
#include <hip/hip_bf16.h>

typedef __attribute__((ext_vector_type(4))) float f32x4;
typedef __attribute__((ext_vector_type(8))) short s16x8;
typedef __attribute__((ext_vector_type(4))) short s16x4;

#define DI __device__ __forceinline__

static constexpr int B_ = 8, S_ = 2048, E_ = 300, EP_ = 320, HD_ = 512, G4_ = 2048;
static constexpr int C_ = 8921, RNN_ = 1024, NROW_ = 16384;

DI float bf2f(unsigned short u){ unsigned int x = ((unsigned int)u) << 16; return __builtin_bit_cast(float, x); }
DI unsigned short f2bf(float f){
  unsigned int x = __builtin_bit_cast(unsigned int, f);
  x += 0x7fff + ((x >> 16) & 1);
  return (unsigned short)(x >> 16);
}
DI float sigm(float x){ return 1.f / (1.f + __expf(-x)); }
DI float tanh_f(float x){
  x = fminf(fmaxf(x, -15.f), 15.f);
  float e = __expf(2.f * x);
  return (e - 1.f) / (e + 1.f);
}
DI void gload16(const void* g, void* l){
  __builtin_amdgcn_global_load_lds((const __attribute__((address_space(1))) void*)g,
                                   (__attribute__((address_space(3))) void*)l, 16, 0, 0);
}
DI unsigned has_sent(unsigned x){   // any bf16 half == 0xFFFF (sentinel NaN)?
  return (unsigned)(((x & 0xFFFFu) == 0xFFFFu) | ((x >> 16) == 0xFFFFu));
}

// ---------------- convert / pad fp32 -> bf16 ----------------
__global__ void k_cvt_pad(const float* __restrict__ src, unsigned short* __restrict__ dst,
                          int Rs, int Cs, int Cd){
  int r = blockIdx.x;
  long db = (long)r * Cd;
  for (int c = threadIdx.x; c < Cd; c += blockDim.x){
    float v = (r < Rs && c < Cs) ? src[(long)r * Cs + c] : 0.f;
    dst[db + c] = f2bf(v);
  }
}

// ---------------- embedding gather -> xe [S][B][EP] bf16 ----------------
__global__ void k_embed(const int* __restrict__ text, const float* __restrict__ emb,
                        unsigned short* __restrict__ xe){
  int m = blockIdx.x;            // m = s*8 + b
  int s = m >> 3, b = m & 7;
  int tok = text[b * S_ + s];
  const float* e = emb + (long)tok * E_;
  long db = (long)m * EP_;
  for (int c = threadIdx.x; c < EP_; c += blockDim.x){
    float v = (c < E_) ? e[c] : 0.f;
    xe[db + c] = f2bf(v);
  }
}

// ---------------- gemm_bt: C[M,N] = A[M,K] * Bt[N,K]^T  (bf16 in, fp32 acc) --------
// EPI: 0 = fp32 store, 1 = bf16 tanh, 2 = bf16 + bias, 3 = bf16
template<int EPI>
__global__ __launch_bounds__(256, 2)
void k_gemm_bt(const unsigned short* __restrict__ A, const unsigned short* __restrict__ Bt,
               void* __restrict__ Cout, int N, int K, int Mreal,
               long aBatch, long bBatch, long cBatch, const float* __restrict__ bias){
  __shared__ unsigned short As[128 * 32];
  __shared__ unsigned short Bs[128 * 32];
  const int tid = threadIdx.x, lane = tid & 63, wid = tid >> 6;
  const int wm = wid >> 1, wn = wid & 1;
  const int bm0 = blockIdx.y * 128, bn0 = blockIdx.x * 128;
  A  += (long)blockIdx.z * aBatch;
  Bt += (long)blockIdx.z * bBatch;

  f32x4 acc[4][4];
#pragma unroll
  for (int i = 0; i < 4; ++i)
#pragma unroll
    for (int jx = 0; jx < 4; ++jx) acc[i][jx] = f32x4{0.f, 0.f, 0.f, 0.f};

  for (int k0 = 0; k0 < K; k0 += 32){
    __syncthreads();
#pragma unroll
    for (int cc = 0; cc < 2; ++cc){
      int e = tid + cc * 256;               // 0..511 : 16B segment index
      int row = e >> 2, seg = e & 3;
      const unsigned short* ga = A + ((long)(bm0 + row)) * K + k0 + seg * 8;
      gload16(ga, (char*)As + cc * 4096 + wid * 1024);
      const unsigned short* gb = Bt + ((long)(bn0 + row)) * K + k0 + seg * 8;
      gload16(gb, (char*)Bs + cc * 4096 + wid * 1024);
    }
    __syncthreads();
    s16x8 af[4], bfr[4];
#pragma unroll
    for (int mt = 0; mt < 4; ++mt){
      int arow = wm * 64 + mt * 16 + (lane & 15);
      af[mt] = *(const s16x8*)((const char*)As + arow * 64 + (lane >> 4) * 16);
    }
#pragma unroll
    for (int nt = 0; nt < 4; ++nt){
      int brow = wn * 64 + nt * 16 + (lane & 15);
      bfr[nt] = *(const s16x8*)((const char*)Bs + brow * 64 + (lane >> 4) * 16);
    }
#pragma unroll
    for (int mt = 0; mt < 4; ++mt)
#pragma unroll
      for (int nt = 0; nt < 4; ++nt)
        acc[mt][nt] = __builtin_amdgcn_mfma_f32_16x16x32_bf16(af[mt], bfr[nt], acc[mt][nt], 0, 0, 0);
  }

  long co = (long)blockIdx.z * cBatch;
#pragma unroll
  for (int mt = 0; mt < 4; ++mt){
#pragma unroll
    for (int r = 0; r < 4; ++r){
      int row = bm0 + wm * 64 + mt * 16 + (lane >> 4) * 4 + r;
      if (row < Mreal){
#pragma unroll
        for (int nt = 0; nt < 4; ++nt){
          int col = bn0 + wn * 64 + nt * 16 + (lane & 15);
          float v = acc[mt][nt][r];
          long idx = co + (long)row * N + col;
          if constexpr (EPI == 0) ((float*)Cout)[idx] = v;
          else if constexpr (EPI == 1) ((unsigned short*)Cout)[idx] = f2bf(tanh_f(v));
          else if constexpr (EPI == 2) ((unsigned short*)Cout)[idx] = f2bf(v + bias[col]);
          else ((unsigned short*)Cout)[idx] = f2bf(v);
        }
      }
    }
  }
}

// ---------------- persistent bi-LSTM recurrence ----------------
// 32 WGs: wg<16 forward, wg>=16 backward. Each WG owns 32 h-dims (j0..j0+31) for all
// 8 batches; its 128 Whh rows (i,f,g,o quadruple) live in VGPRs as MFMA B-fragments.
// Cross-WG handshake: DATA-AS-FLAG. Hb is pre-memset to 0xFFFF (bf16 NaN — the
// recurrence can never produce it). Producers store h with sc0+sc1 (write-through
// to the coherent point) and DO NOT wait. Consumers busy-poll their own 16B chunks
// of h(t-1) with sc0+sc1 loads until sentinel-free; the successful poll IS the
// load. Addresses are step-unique -> no ABA. No fences anywhere (agent fences
// lower to whole-L2 buffer_inv/wbl2 and wreck L2 residency of xw).
__global__ __launch_bounds__(256, 1)
void k_lstm(const unsigned short* __restrict__ xw_all,
            const float* __restrict__ Whh_f, const float* __restrict__ Whh_b,
            unsigned short* __restrict__ Hb){
  __shared__ unsigned short hA[16 * 512];   // A tile [16 rows=batch][512 k], swizzled
  __shared__ float gl[8 * 128];             // gate results [batch][128 local gates]
  char* hAc = (char*)hA;
  const int tid = threadIdx.x, lane = tid & 63, wave = tid >> 6;
  const int wg = blockIdx.x;
  const int dir = wg >> 4, w16 = wg & 15;
  const int j0 = w16 * 32;
  const int b8 = tid >> 5, j = tid & 31;
  const float* Whh = dir ? Whh_b : Whh_f;
  const unsigned short* xw = xw_all + (long)dir * NROW_ * G4_;

  // preload Whh slice into register B-fragments. local gate row lr = q*32 + jj
  s16x8 Bf0[16], Bf1[16];
  {
    int lr0 = wave * 32 + (lane & 15);
    int lr1 = lr0 + 16;
    int kg = (lane >> 4) * 8;
    const float* r0 = Whh + (long)((lr0 >> 5) * 512 + j0 + (lr0 & 31)) * 512;
    const float* r1 = Whh + (long)((lr1 >> 5) * 512 + j0 + (lr1 & 31)) * 512;
#pragma unroll
    for (int kt = 0; kt < 16; ++kt){
      s16x8 v0, v1;
#pragma unroll
      for (int i = 0; i < 8; ++i){
        v0[i] = (short)f2bf(r0[kt * 32 + kg + i]);
        v1[i] = (short)f2bf(r1[kt * 32 + kg + i]);
      }
      Bf0[kt] = v0; Bf1[kt] = v1;
    }
  }
  for (int i = tid; i < 16 * 512; i += 256) hA[i] = 0;

  float creg = 0.f;
  float xwi, xwf, xwg, xwo;
  {
    int s0 = dir ? (S_ - 1) : 0;
    long base = ((long)s0 * 8 + b8) * G4_ + j0 + j;
    xwi = bf2f(xw[base]); xwf = bf2f(xw[base + 512]);
    xwg = bf2f(xw[base + 1024]); xwo = bf2f(xw[base + 1536]);
  }
  // this thread's two 16B chunks of the h(t-1) tile (rows bp0 and bp0+4)
  const int bp0 = tid >> 6, seg0 = tid & 63;
  const int lds0 = (bp0 * 1024 + seg0 * 16) ^ ((bp0 & 7) << 4);
  const int lds1 = ((bp0 + 4) * 1024 + seg0 * 16) ^ (((bp0 + 4) & 7) << 4);
  __syncthreads();

  for (int t = 0; t < S_; ++t){
    int s = dir ? (S_ - 1 - t) : t;
    if (t > 0){
      int sp = dir ? (s + 1) : (s - 1);
      const uint4* gp0 = (const uint4*)(Hb + ((long)bp0 * S_ + sp) * RNN_ + dir * HD_) + seg0;
      const uint4* gp1 = (const uint4*)(Hb + ((long)(bp0 + 4) * S_ + sp) * RNN_ + dir * HD_) + seg0;
      uint4 va0, va1;
      for (;;){
        asm volatile("global_load_dwordx4 %0, %2, off sc0 sc1\n\t"
                     "global_load_dwordx4 %1, %3, off sc0 sc1\n\t"
                     "s_waitcnt vmcnt(0)"
                     : "=&v"(va0), "=&v"(va1) : "v"(gp0), "v"(gp1) : "memory");
        unsigned bad = has_sent(va0.x) | has_sent(va0.y) | has_sent(va0.z) | has_sent(va0.w)
                     | has_sent(va1.x) | has_sent(va1.y) | has_sent(va1.z) | has_sent(va1.w);
        if (!bad) break;
      }
      __builtin_amdgcn_sched_barrier(0);
      *(uint4*)(hAc + lds0) = va0;
      *(uint4*)(hAc + lds1) = va1;
      __syncthreads();
    }

    // gates[16(batch,pad)][128] += hA * Whh_slice^T   (two 8-deep MFMA chains)
    f32x4 acc0a = {0.f,0.f,0.f,0.f}, acc1a = {0.f,0.f,0.f,0.f};
    f32x4 acc0b = {0.f,0.f,0.f,0.f}, acc1b = {0.f,0.f,0.f,0.f};
    {
      int arow = lane & 15;
      int sw = (arow & 7) << 4;
      int kg16 = (lane >> 4) * 16;
#pragma unroll
      for (int kt = 0; kt < 16; kt += 2){
        int ab0 = (arow * 1024 + kt * 64 + kg16) ^ sw;
        int ab1 = (arow * 1024 + (kt + 1) * 64 + kg16) ^ sw;
        s16x8 afr0 = *(const s16x8*)(hAc + ab0);
        s16x8 afr1 = *(const s16x8*)(hAc + ab1);
        acc0a = __builtin_amdgcn_mfma_f32_16x16x32_bf16(afr0, Bf0[kt], acc0a, 0, 0, 0);
        acc1a = __builtin_amdgcn_mfma_f32_16x16x32_bf16(afr0, Bf1[kt], acc1a, 0, 0, 0);
        acc0b = __builtin_amdgcn_mfma_f32_16x16x32_bf16(afr1, Bf0[kt + 1], acc0b, 0, 0, 0);
        acc1b = __builtin_amdgcn_mfma_f32_16x16x32_bf16(afr1, Bf1[kt + 1], acc1b, 0, 0, 0);
      }
    }
    f32x4 acc0 = acc0a + acc0b, acc1 = acc1a + acc1b;
    {
      int colb = wave * 32 + (lane & 15);
      int rb = (lane >> 4) * 4;
#pragma unroll
      for (int r = 0; r < 4; ++r){
        int row = rb + r;
        if (row < 8){
          gl[row * 128 + colb] = acc0[r];
          gl[row * 128 + colb + 16] = acc1[r];
        }
      }
    }
    __syncthreads();
    {
      float gi = gl[b8 * 128 + j]      + xwi;
      float gf = gl[b8 * 128 + 32 + j] + xwf;
      float gg = gl[b8 * 128 + 64 + j] + xwg;
      float go = gl[b8 * 128 + 96 + j] + xwo;
      creg = sigm(gf) * creg + sigm(gi) * tanh_f(gg);
      float hv = sigm(go) * tanh_f(creg);
      unsigned short* hp = Hb + ((long)b8 * S_ + s) * RNN_ + dir * HD_ + j0 + j;
      unsigned hd = (unsigned)f2bf(hv);
      asm volatile("global_store_short %0, %1, off sc0 sc1"
                   :: "v"(hp), "v"(hd) : "memory");
      // prefetch next step's xw (overlaps the next poll)
      if (t + 1 < S_){
        int sn = dir ? (s - 1) : (s + 1);
        long base = ((long)sn * 8 + b8) * G4_ + j0 + j;
        xwi = bf2f(xw[base]); xwf = bf2f(xw[base + 512]);
        xwg = bf2f(xw[base + 1024]); xwo = bf2f(xw[base + 1536]);
      }
    }
  }
}

// ---------------- fused softmax (over s) + logits ----------------
__global__ __launch_bounds__(256)
void k_softmax_logits(float* __restrict__ alpha, const unsigned short* __restrict__ HOt,
                      const float* __restrict__ Ob, float* __restrict__ logits){
  const int lane = threadIdx.x & 63, wv = threadIdx.x >> 6;
  long row = (long)blockIdx.x * 4 + wv;       // row = b*C + c
  float* a = alpha + row * (long)S_;
  const unsigned short* h = HOt + row * (long)S_;
  float v[32];
  float mx = -1e30f;
#pragma unroll
  for (int jj = 0; jj < 8; ++jj){
    f32x4 t = *(const f32x4*)(a + jj * 256 + lane * 4);
#pragma unroll
    for (int r = 0; r < 4; ++r){ v[jj * 4 + r] = t[r]; mx = fmaxf(mx, t[r]); }
  }
#pragma unroll
  for (int o = 32; o > 0; o >>= 1) mx = fmaxf(mx, __shfl_xor(mx, o));
  float sum = 0.f;
#pragma unroll
  for (int i = 0; i < 32; ++i){ v[i] = __expf(v[i] - mx); sum += v[i]; }
#pragma unroll
  for (int o = 32; o > 0; o >>= 1) sum += __shfl_xor(sum, o);
  float inv = 1.f / sum;
  float dot = 0.f;
#pragma unroll
  for (int jj = 0; jj < 8; ++jj){
    s16x4 hv = *(const s16x4*)(h + jj * 256 + lane * 4);
    f32x4 av;
#pragma unroll
    for (int r = 0; r < 4; ++r){
      float al = v[jj * 4 + r] * inv;
      av[r] = al;
      dot += al * bf2f((unsigned short)hv[r]);
    }
    *(f32x4*)(a + jj * 256 + lane * 4) = av;
  }
#pragma unroll
  for (int o = 32; o > 0; o >>= 1) dot += __shfl_xor(dot, o);
  if (lane == 0){
    int c = (int)(row % C_);
    logits[row] = dot + Ob[c];
  }
}

// ---------------- host ----------------
extern "C" void kernel_launch(void* const* d_in, const int* in_sizes, int n_in,
                              void* d_out, int out_size, void* d_ws, size_t ws_size,
                              hipStream_t stream){
  const int*   text  = (const int*)d_in[0];
  const float* emb   = (const float*)d_in[2];
  const float* Wih_f = (const float*)d_in[3];
  const float* Whh_f = (const float*)d_in[4];
  const float* b_f   = (const float*)d_in[5];
  const float* Wih_b = (const float*)d_in[6];
  const float* Whh_b = (const float*)d_in[7];
  const float* b_b   = (const float*)d_in[8];
  const float* Ww    = (const float*)d_in[9];
  const float* Qw    = (const float*)d_in[10];
  const float* Ow    = (const float*)d_in[11];
  const float* Ob    = (const float*)d_in[12];

  char* ws = (char*)d_ws;
  long o = 0;
  unsigned short* wWihF = (unsigned short*)(ws + o); o += 2048L * 320 * 2;
  unsigned short* wWihB = (unsigned short*)(ws + o); o += 2048L * 320 * 2;
  unsigned short* wWw   = (unsigned short*)(ws + o); o += 512L * 1024 * 2;
  unsigned short* wQw   = (unsigned short*)(ws + o); o += 8960L * 512 * 2;
  unsigned short* wOw   = (unsigned short*)(ws + o); o += 8960L * 1024 * 2;
  unsigned short* wH    = (unsigned short*)(ws + o); o += 8L * 2048 * 1024 * 2;
  unsigned short* wZ    = (unsigned short*)(ws + o); o += 16384L * 512 * 2;
  char* regA = ws + o;                                // reused region
  unsigned short* wXe  = (unsigned short*)regA;                         // [16384][320]
  unsigned short* wXw  = (unsigned short*)(regA + 16384L * 320 * 2);    // [2][16384][2048]
  unsigned short* wHOt = (unsigned short*)regA;                         // [8][8921][2048] (after LSTM)

  float* logits = (float*)d_out;
  float* alpha  = logits + 8L * C_;    // [8][8921][2048], also holds raw scores

  // re-arm the data-as-flag sentinel every launch (graph-replay safe)
  hipMemsetAsync(wH, 0xFF, 8L * 2048 * 1024 * 2, stream);
  k_cvt_pad<<<2048, 256, 0, stream>>>(Wih_f, wWihF, 2048, 300, 320);
  k_cvt_pad<<<2048, 256, 0, stream>>>(Wih_b, wWihB, 2048, 300, 320);
  k_cvt_pad<<<512,  256, 0, stream>>>(Ww, wWw, 512, 1024, 1024);
  k_cvt_pad<<<8960, 256, 0, stream>>>(Qw, wQw, 8921, 512, 512);
  k_cvt_pad<<<8960, 256, 0, stream>>>(Ow, wOw, 8921, 1024, 1024);
  k_embed<<<16384, 256, 0, stream>>>(text, emb, wXe);

  // xw[dir] = xe @ Wih^T + b  -> bf16 [16384][2048]
  k_gemm_bt<2><<<dim3(16, 128, 1), 256, 0, stream>>>(wXe, wWihF, wXw, 2048, 320, 16384, 0, 0, 0, b_f);
  k_gemm_bt<2><<<dim3(16, 128, 1), 256, 0, stream>>>(wXe, wWihB, wXw + 16384L * 2048, 2048, 320, 16384, 0, 0, 0, b_b);

  k_lstm<<<32, 256, 0, stream>>>(wXw, Whh_f, Whh_b, wH);

  // Z = tanh(H @ Ww^T)  [16384][512] bf16
  k_gemm_bt<1><<<dim3(4, 128, 1), 256, 0, stream>>>(wH, wWw, wZ, 512, 1024, 16384, 0, 0, 0, nullptr);
  // scores[b] = Qw @ Z[b]^T  -> fp32 into alpha region
  k_gemm_bt<0><<<dim3(16, 70, 8), 256, 0, stream>>>(wQw, wZ, alpha, 2048, 512, C_, 0, 2048L * 512, (long)C_ * 2048, nullptr);
  // HOt[b] = Ow @ H[b]^T  -> bf16
  k_gemm_bt<3><<<dim3(16, 70, 8), 256, 0, stream>>>(wOw, wH, wHOt, 2048, 1024, C_, 0, 2048L * 1024, (long)C_ * 2048, nullptr);

  k_softmax_logits<<<17842, 256, 0, stream>>>(alpha, wHOt, Ob, logits);
}